// Round 1
// baseline (130.809 us; speedup 1.0000x reference)
//
#include <hip/hip_runtime.h>
#include <hip/hip_fp16.h>

#define RESG 128
#define NVOX (RESG * RESG * RESG)
#define NCH 28
#define NPAD 32
#define NSAMP 444

static __device__ __forceinline__ __half2 u_as_h2(unsigned int u) {
    union { unsigned int u; __half2 h; } c;
    c.u = u;
    return c.h;
}

// Transpose [C][Z][Y][X] f32 -> [Z][Y][X][C(pad 32)] fp16. One voxel = 64B = 1 line.
__global__ __launch_bounds__(256) void xpose_k(const float* __restrict__ src,
                                               __half* __restrict__ dst) {
    const int v = blockIdx.x * 256 + threadIdx.x;
    unsigned int w[16];
#pragma unroll
    for (int j = 0; j < 14; ++j) {
        __half2 h = __floats2half2_rn(src[(size_t)(2 * j) * NVOX + v],
                                      src[(size_t)(2 * j + 1) * NVOX + v]);
        union { __half2 h; unsigned int u; } c;
        c.h = h;
        w[j] = c.u;
    }
    w[14] = 0u;
    w[15] = 0u;
    uint4* dp = reinterpret_cast<uint4*>(dst + (size_t)v * NPAD);
    dp[0] = make_uint4(w[0], w[1], w[2], w[3]);
    dp[1] = make_uint4(w[4], w[5], w[6], w[7]);
    dp[2] = make_uint4(w[8], w[9], w[10], w[11]);
    dp[3] = make_uint4(w[12], w[13], w[14], w[15]);
}

// One wave (64 lanes) per ray. Lane j handles samples j, j+64, ... of that ray.
template <bool TR>
__global__ __launch_bounds__(256) void render_k(const float* __restrict__ ro,
                                                const float* __restrict__ rd,
                                                const void* __restrict__ gptr,
                                                float* __restrict__ out, int B) {
    const int ray = (int)((blockIdx.x * (size_t)blockDim.x + threadIdx.x) >> 6);
    const int lane = (int)(threadIdx.x & 63);
    if (ray >= B) return;

    const float RAD = 1.3f;
    const float STEPF = (float)(1.3 * 2.0 / 128.0 / 2.0);

    const float ox = ro[ray * 3 + 0], oy = ro[ray * 3 + 1], oz = ro[ray * 3 + 2];
    const float dxr = rd[ray * 3 + 0], dyr = rd[ray * 3 + 1], dzr = rd[ray * 3 + 2];

    const float ivx = 1.0f / dxr, ivy = 1.0f / dyr, ivz = 1.0f / dzr;
    const float t0x = (-RAD - ox) * ivx, t1x = (RAD - ox) * ivx;
    const float t0y = (-RAD - oy) * ivy, t1y = (RAD - oy) * ivy;
    const float t0z = (-RAD - oz) * ivz, t1z = (RAD - oz) * ivz;
    float tmin = fmaxf(fmaxf(fminf(t0x, t1x), fminf(t0y, t1y)), fminf(t0z, t1z));
    tmin = fmaxf(tmin, 0.0f);
    const float tmax = fminf(fminf(fmaxf(t0x, t1x), fmaxf(t0y, t1y)), fmaxf(t0z, t1z));

    const float nrm = sqrtf(dxr * dxr + dyr * dyr + dzr * dzr);
    const float dist = STEPF * nrm;

    const float inn = 1.0f / (nrm + 1e-9f);
    const float x = dxr * inn, y = dyr * inn, z = dzr * inn;
    float sh[9];
    sh[0] = 0.28209479177387814f;
    sh[1] = -0.4886025119029199f * y;
    sh[2] = 0.4886025119029199f * z;
    sh[3] = -0.4886025119029199f * x;
    sh[4] = 1.0925484305920792f * x * y;
    sh[5] = -1.0925484305920792f * y * z;
    sh[6] = 0.31539156525252005f * (2.0f * z * z - x * x - y * y);
    sh[7] = -1.0925484305920792f * x * z;
    sh[8] = 0.5462742152960396f * (x * x - y * y);

    float accR = 0.f, accG = 0.f, accB = 0.f, accA = 0.f;
    float T = 1.0f;

    if (tmin < tmax) {
        for (int chk = 0; chk < 7; ++chk) {
            const float tb = tmin + (float)(chk * 64) * STEPF;
            if (tb >= tmax) break;  // uniform over wave: all later samples dead
            const int sidx = chk * 64 + lane;
            const float t = tmin + (float)sidx * STEPF;
            const float px = ox + dxr * t, py = oy + dyr * t, pz = oz + dzr * t;
            const bool live = (sidx < NSAMP) && (t < tmax) && (fabsf(px) <= RAD) &&
                              (fabsf(py) <= RAD) && (fabsf(pz) <= RAD);
            float alpha = 0.f, cr = 0.f, cg = 0.f, cb = 0.f;
            if (live) {
                float gx = fminf(fmaxf((px / RAD + 1.0f) * 0.5f * 127.0f, 0.0f), 127.0f);
                float gy = fminf(fmaxf((py / RAD + 1.0f) * 0.5f * 127.0f, 0.0f), 127.0f);
                float gz = fminf(fmaxf((pz / RAD + 1.0f) * 0.5f * 127.0f, 0.0f), 127.0f);
                const int x0 = min((int)gx, 126);
                const int y0 = min((int)gy, 126);
                const int z0 = min((int)gz, 126);
                const float fx = gx - (float)x0;
                const float fy = gy - (float)y0;
                const float fz = gz - (float)z0;
                float f[NCH];
                if constexpr (TR) {
                    const __half* gbuf = (const __half*)gptr;
                    const size_t base = (size_t)((z0 * RESG + y0) * RESG + x0) * NPAD;
                    __half2 a2[14];
#pragma unroll
                    for (int j = 0; j < 14; ++j) a2[j] = __float2half2_rn(0.0f);
#pragma unroll
                    for (int c8 = 0; c8 < 8; ++c8) {
                        const int dzi = c8 >> 2, dyi = (c8 >> 1) & 1, dxi = c8 & 1;
                        const float wgt = (dzi ? fz : 1.0f - fz) * (dyi ? fy : 1.0f - fy) *
                                          (dxi ? fx : 1.0f - fx);
                        const __half* cp = gbuf + base + dzi * (RESG * RESG * NPAD) +
                                           dyi * (RESG * NPAD) + dxi * NPAD;
                        const uint4 q0 = *reinterpret_cast<const uint4*>(cp);
                        const uint4 q1 = *reinterpret_cast<const uint4*>(cp + 8);
                        const uint4 q2 = *reinterpret_cast<const uint4*>(cp + 16);
                        const uint2 q3 = *reinterpret_cast<const uint2*>(cp + 24);
                        const __half2 wh = __float2half2_rn(wgt);
                        a2[0] = __hfma2(u_as_h2(q0.x), wh, a2[0]);
                        a2[1] = __hfma2(u_as_h2(q0.y), wh, a2[1]);
                        a2[2] = __hfma2(u_as_h2(q0.z), wh, a2[2]);
                        a2[3] = __hfma2(u_as_h2(q0.w), wh, a2[3]);
                        a2[4] = __hfma2(u_as_h2(q1.x), wh, a2[4]);
                        a2[5] = __hfma2(u_as_h2(q1.y), wh, a2[5]);
                        a2[6] = __hfma2(u_as_h2(q1.z), wh, a2[6]);
                        a2[7] = __hfma2(u_as_h2(q1.w), wh, a2[7]);
                        a2[8] = __hfma2(u_as_h2(q2.x), wh, a2[8]);
                        a2[9] = __hfma2(u_as_h2(q2.y), wh, a2[9]);
                        a2[10] = __hfma2(u_as_h2(q2.z), wh, a2[10]);
                        a2[11] = __hfma2(u_as_h2(q2.w), wh, a2[11]);
                        a2[12] = __hfma2(u_as_h2(q3.x), wh, a2[12]);
                        a2[13] = __hfma2(u_as_h2(q3.y), wh, a2[13]);
                    }
#pragma unroll
                    for (int j = 0; j < 14; ++j) {
                        const float2 t2 = __half22float2(a2[j]);
                        f[2 * j] = t2.x;
                        f[2 * j + 1] = t2.y;
                    }
                } else {
                    const float* gf = (const float*)gptr;
                    const size_t cell = (size_t)(z0 * RESG + y0) * RESG + x0;
#pragma unroll
                    for (int c = 0; c < NCH; ++c) f[c] = 0.0f;
#pragma unroll
                    for (int c8 = 0; c8 < 8; ++c8) {
                        const int dzi = c8 >> 2, dyi = (c8 >> 1) & 1, dxi = c8 & 1;
                        const float wgt = (dzi ? fz : 1.0f - fz) * (dyi ? fy : 1.0f - fy) *
                                          (dxi ? fx : 1.0f - fx);
                        const float* p = gf + cell + dzi * (RESG * RESG) + dyi * RESG + dxi;
#pragma unroll
                        for (int c = 0; c < NCH; ++c) f[c] += wgt * p[(size_t)c * NVOX];
                    }
                }
                const float sigma = fmaxf(f[27], 0.0f);
                float r = 0.f, g = 0.f, b = 0.f;
#pragma unroll
                for (int k = 0; k < 9; ++k) {
                    r += sh[k] * f[k];
                    g += sh[k] * f[9 + k];
                    b += sh[k] * f[18 + k];
                }
                alpha = 1.0f - __expf(-sigma * dist);
                cr = 1.0f / (1.0f + __expf(-r));
                cg = 1.0f / (1.0f + __expf(-g));
                cb = 1.0f / (1.0f + __expf(-b));
            }
            // wave-wide exclusive prefix product of (1-alpha+1e-10)
            const float wfac = 1.0f - alpha + 1e-10f;
            float incl = wfac;
#pragma unroll
            for (int off = 1; off < 64; off <<= 1) {
                const float u = __shfl_up(incl, off);
                if (lane >= off) incl *= u;
            }
            float excl = __shfl_up(incl, 1);
            if (lane == 0) excl = 1.0f;
            const float al = alpha * (T * excl);
            accR += al * cr;
            accG += al * cg;
            accB += al * cb;
            accA += al;
            T *= __shfl(incl, 63);
        }
    }
#pragma unroll
    for (int off = 32; off; off >>= 1) {
        accR += __shfl_xor(accR, off);
        accG += __shfl_xor(accG, off);
        accB += __shfl_xor(accB, off);
        accA += __shfl_xor(accA, off);
    }
    if (lane == 0) {
        const float bg = 1.0f - accA;
        out[ray * 3 + 0] = accR + bg;
        out[ray * 3 + 1] = accG + bg;
        out[ray * 3 + 2] = accB + bg;
    }
}

extern "C" void kernel_launch(void* const* d_in, const int* in_sizes, int n_in,
                              void* d_out, int out_size, void* d_ws, size_t ws_size,
                              hipStream_t stream) {
    const float* rays_o = (const float*)d_in[0];
    const float* rays_d = (const float*)d_in[1];
    const float* data = (const float*)d_in[2];
    float* out = (float*)d_out;
    const int B = in_sizes[0] / 3;

    const size_t need = (size_t)NVOX * NPAD * sizeof(__half);  // 128 MiB
    const int nthreads = B * 64;
    const int nblocks = (nthreads + 255) / 256;

    if (d_ws != nullptr && ws_size >= need) {
        __half* grid16 = (__half*)d_ws;
        xpose_k<<<NVOX / 256, 256, 0, stream>>>(data, grid16);
        render_k<true><<<nblocks, 256, 0, stream>>>(rays_o, rays_d, (const void*)grid16, out, B);
    } else {
        render_k<false><<<nblocks, 256, 0, stream>>>(rays_o, rays_d, (const void*)data, out, B);
    }
}